// Round 1
// baseline (765.632 us; speedup 1.0000x reference)
//
#include <hip/hip_runtime.h>
#include <hip/hip_bf16.h>

// Problem: B=2, H=16, S=2048, D=64 fp32 attention, returns (output, attention).
// d_out = [B,H,S,D] output (4,194,304 floats) ++ [B,H,S,S] attention (134,217,728 floats).
// Strategy: fused 2-pass (stats then normalize+PV) per 64-row q-tile, bf16 MFMA compute,
// since the 537 MB attention write is the roofline and recompute of QK^T is ~free on MFMA.

#define S_LEN 2048
#define D_DIM 64
#define BM 64
#define BN 64
#define NT (S_LEN / BN)   // 32 key tiles
#define LDP 72            // padded LDS row stride in bf16 elems (144 B -> bank-shift 4)

typedef __attribute__((ext_vector_type(8))) short bf16x8;
typedef __attribute__((ext_vector_type(4))) float f32x4;

__device__ __forceinline__ unsigned short f2bf(float x) {
    unsigned u = __float_as_uint(x);
    u += 0x7FFF + ((u >> 16) & 1);   // round-to-nearest-even
    return (unsigned short)(u >> 16);
}

__global__ __launch_bounds__(256, 4)
void attn_kernel(const float* __restrict__ Qg, const float* __restrict__ Kg,
                 const float* __restrict__ Vg, const int* __restrict__ Mg,
                 float* __restrict__ Og, float* __restrict__ Ag) {
    __shared__ unsigned short Qs[BM * LDP];
    __shared__ unsigned short Ks[BN * LDP];
    __shared__ unsigned short Vts[D_DIM * LDP];   // transposed: [d][key]
    __shared__ unsigned short Ps[BM * LDP];
    __shared__ int maskS[BN];

    const int tid  = threadIdx.x;
    const int w    = tid >> 6;      // wave 0..3 -> q rows [w*16, w*16+16)
    const int lane = tid & 63;
    const int l15  = lane & 15;
    const int quad = lane >> 4;

    const int qt = blockIdx.x;      // q tile 0..31
    const int bh = blockIdx.y;      // 0..31
    const int b  = bh >> 4;
    const int q0 = qt * BM;

    const float* Qb = Qg + ((size_t)bh * S_LEN + q0) * D_DIM;
    const float* Kb = Kg + (size_t)bh * S_LEN * D_DIM;
    const float* Vb = Vg + (size_t)bh * S_LEN * D_DIM;
    const int*   Mb = Mg + (size_t)b * S_LEN;
    float* Ob = Og + ((size_t)bh * S_LEN + q0) * D_DIM;
    float* Ab = Ag + ((size_t)bh * S_LEN + q0) * (size_t)S_LEN;

    // ---- stage Q tile, scaled by 1/TEMPERATURE, as bf16 ----
    {
        const float sc = 1.0f / 32.0f;
        #pragma unroll
        for (int i = 0; i < 4; ++i) {
            int f = tid + i * 256;          // float4 index 0..1023
            int row = f >> 4, c4 = f & 15;
            const float4 v = *(const float4*)(Qb + row * D_DIM + c4 * 4);
            unsigned lo = f2bf(v.x * sc) | ((unsigned)f2bf(v.y * sc) << 16);
            unsigned hi = f2bf(v.z * sc) | ((unsigned)f2bf(v.w * sc) << 16);
            *(uint2*)(&Qs[row * LDP + c4 * 4]) = make_uint2(lo, hi);
        }
    }
    __syncthreads();

    // Preload Q A-fragments (reused for every k-tile in both passes).
    // A layout: A[m = l15][k = quad*8 + j], m is tile row w*16 + l15.
    bf16x8 aq[2];
    #pragma unroll
    for (int ks = 0; ks < 2; ++ks)
        aq[ks] = *(const bf16x8*)(&Qs[(w * 16 + l15) * LDP + ks * 32 + quad * 8]);

    // ================= Pass 1: row sums of exp(s) =================
    float lsum[4] = {0.f, 0.f, 0.f, 0.f};

    for (int kt = 0; kt < NT; ++kt) {
        const int key0 = kt * BN;
        #pragma unroll
        for (int i = 0; i < 4; ++i) {
            int f = tid + i * 256;
            int row = f >> 4, c4 = f & 15;
            const float4 v = *(const float4*)(Kb + (size_t)(key0 + row) * D_DIM + c4 * 4);
            unsigned lo = f2bf(v.x) | ((unsigned)f2bf(v.y) << 16);
            unsigned hi = f2bf(v.z) | ((unsigned)f2bf(v.w) << 16);
            *(uint2*)(&Ks[row * LDP + c4 * 4]) = make_uint2(lo, hi);
        }
        if (tid < BN) maskS[tid] = Mb[key0 + tid];
        __syncthreads();

        #pragma unroll
        for (int cb = 0; cb < 4; ++cb) {
            f32x4 acc = {0.f, 0.f, 0.f, 0.f};
            #pragma unroll
            for (int ks = 0; ks < 2; ++ks) {
                bf16x8 bk = *(const bf16x8*)(&Ks[(cb * 16 + l15) * LDP + ks * 32 + quad * 8]);
                acc = __builtin_amdgcn_mfma_f32_16x16x32_bf16(aq[ks], bk, acc, 0, 0, 0);
            }
            const int mk = maskS[cb * 16 + l15];
            #pragma unroll
            for (int r = 0; r < 4; ++r) {
                float s = mk ? acc[r] : -1e9f;
                lsum[r] += __expf(s);
            }
        }
        __syncthreads();
    }

    // Reduce across the 16 lanes (same rows, different cols) -> 1/l per row.
    #pragma unroll
    for (int r = 0; r < 4; ++r) {
        float v = lsum[r];
        v += __shfl_xor(v, 1);
        v += __shfl_xor(v, 2);
        v += __shfl_xor(v, 4);
        v += __shfl_xor(v, 8);
        lsum[r] = 1.0f / v;
    }

    // ================= Pass 2: write P, accumulate O = P V =================
    f32x4 oacc[4];
    #pragma unroll
    for (int db = 0; db < 4; ++db) oacc[db] = (f32x4){0.f, 0.f, 0.f, 0.f};

    for (int kt = 0; kt < NT; ++kt) {
        const int key0 = kt * BN;
        // stage K tile
        #pragma unroll
        for (int i = 0; i < 4; ++i) {
            int f = tid + i * 256;
            int row = f >> 4, c4 = f & 15;
            const float4 v = *(const float4*)(Kb + (size_t)(key0 + row) * D_DIM + c4 * 4);
            unsigned lo = f2bf(v.x) | ((unsigned)f2bf(v.y) << 16);
            unsigned hi = f2bf(v.z) | ((unsigned)f2bf(v.w) << 16);
            *(uint2*)(&Ks[row * LDP + c4 * 4]) = make_uint2(lo, hi);
        }
        // stage V tile transposed: Vts[d][key]
        {
            int key = tid & 63, g = tid >> 6;
            #pragma unroll
            for (int i = 0; i < 4; ++i) {
                int d0 = (g * 4 + i) * 4;
                const float4 v = *(const float4*)(Vb + (size_t)(key0 + key) * D_DIM + d0);
                Vts[(d0 + 0) * LDP + key] = f2bf(v.x);
                Vts[(d0 + 1) * LDP + key] = f2bf(v.y);
                Vts[(d0 + 2) * LDP + key] = f2bf(v.z);
                Vts[(d0 + 3) * LDP + key] = f2bf(v.w);
            }
        }
        if (tid < BN) maskS[tid] = Mb[key0 + tid];
        __syncthreads();

        // QK^T, normalize, write attention, stage P (bf16) for PV
        #pragma unroll
        for (int cb = 0; cb < 4; ++cb) {
            f32x4 acc = {0.f, 0.f, 0.f, 0.f};
            #pragma unroll
            for (int ks = 0; ks < 2; ++ks) {
                bf16x8 bk = *(const bf16x8*)(&Ks[(cb * 16 + l15) * LDP + ks * 32 + quad * 8]);
                acc = __builtin_amdgcn_mfma_f32_16x16x32_bf16(aq[ks], bk, acc, 0, 0, 0);
            }
            const int mk  = maskS[cb * 16 + l15];
            const int key = key0 + cb * 16 + l15;
            #pragma unroll
            for (int r = 0; r < 4; ++r) {
                float s = mk ? acc[r] : -1e9f;
                float p = __expf(s) * lsum[r];
                int row = w * 16 + quad * 4 + r;           // C/D: col=l15, row=quad*4+r
                Ab[(size_t)row * S_LEN + key] = p;
                Ps[row * LDP + cb * 16 + l15] = f2bf(p);
            }
        }
        // PV: Ps rows for this wave were written by this wave only -> no barrier
        // (compiler inserts lgkmcnt waits for the same-wave LDS RAW).
        #pragma unroll
        for (int ks2 = 0; ks2 < 2; ++ks2) {
            bf16x8 ap = *(const bf16x8*)(&Ps[(w * 16 + l15) * LDP + ks2 * 32 + quad * 8]);
            #pragma unroll
            for (int db = 0; db < 4; ++db) {
                bf16x8 bv = *(const bf16x8*)(&Vts[(db * 16 + l15) * LDP + ks2 * 32 + quad * 8]);
                oacc[db] = __builtin_amdgcn_mfma_f32_16x16x32_bf16(ap, bv, oacc[db], 0, 0, 0);
            }
        }
        __syncthreads();
    }

    // write O
    #pragma unroll
    for (int db = 0; db < 4; ++db) {
        #pragma unroll
        for (int r = 0; r < 4; ++r) {
            int row = w * 16 + quad * 4 + r;
            Ob[(size_t)row * D_DIM + db * 16 + l15] = oacc[db][r];
        }
    }
}

extern "C" void kernel_launch(void* const* d_in, const int* in_sizes, int n_in,
                              void* d_out, int out_size, void* d_ws, size_t ws_size,
                              hipStream_t stream) {
    const float* q = (const float*)d_in[0];
    const float* k = (const float*)d_in[1];
    const float* v = (const float*)d_in[2];
    const int* mask = (const int*)d_in[3];
    float* out = (float*)d_out;                         // [B,H,S,D]
    float* attn = out + (size_t)2 * 16 * 2048 * 64;     // [B,H,S,S]

    dim3 grid(S_LEN / BM, 2 * 16);
    dim3 block(256);
    attn_kernel<<<grid, block, 0, stream>>>(q, k, v, mask, out, attn);
}